// Round 1
// baseline (1118.665 us; speedup 1.0000x reference)
//
#include <hip/hip_runtime.h>
#include <hip/hip_bf16.h>

#define TK 4096   // tokens
#define DD 2048   // hidden
#define FF 4096   // intermediate
#define NE 8      // experts
#define BM 128
#define BN 128
#define BK 64

typedef __attribute__((ext_vector_type(8))) short bf16x8;
typedef __attribute__((ext_vector_type(4))) short bf16x4;
typedef __attribute__((ext_vector_type(4))) float f32x4;

// byte-offset XOR swizzle for [row][64 bf16] tiles (128B rows): spreads both
// b128 fragment reads and 4x4-transpose b64 writes across all bank groups.
#define SWZ(r) ((((r) & 7) ^ (((r) >> 3) & 7)) << 4)

__device__ __forceinline__ unsigned short f2bf(float f) {
  unsigned u = __builtin_bit_cast(unsigned, f);
  return (unsigned short)((u + 0x7FFFu + ((u >> 16) & 1u)) >> 16);  // RNE
}

__device__ __forceinline__ bf16x4 pack4(float a, float b, float c, float d) {
  bf16x4 r;
  r[0] = (short)f2bf(a); r[1] = (short)f2bf(b);
  r[2] = (short)f2bf(c); r[3] = (short)f2bf(d);
  return r;
}

__device__ __forceinline__ bf16x8 lds_frag(const unsigned short* base, int row, int kbyte) {
  int boff = (row * 128 + kbyte) ^ SWZ(row);
  return *(const bf16x8*)((const char*)base + boff);
}

// ---------------- router: 1 wave per token ----------------
__global__ void k_router(const float* __restrict__ x, const float* __restrict__ gw,
                         int* __restrict__ cnt, int* __restrict__ ltok,
                         float* __restrict__ lw) {
  int tok = (blockIdx.x * blockDim.x + threadIdx.x) >> 6;
  int lane = threadIdx.x & 63;
  if (tok >= TK) return;
  const float* xr = x + (size_t)tok * DD;
  float a0=0,a1=0,a2=0,a3=0,a4=0,a5=0,a6=0,a7=0;
  for (int p = 0; p < DD / 256; ++p) {
    int d0 = p * 256 + lane * 4;
    f32x4 xv = *(const f32x4*)(xr + d0);
#pragma unroll
    for (int j = 0; j < 4; ++j) {
      float xs = xv[j];
      const f32x4* g = (const f32x4*)(gw + (size_t)(d0 + j) * NE);
      f32x4 g0 = g[0], g1 = g[1];
      a0 += xs * g0[0]; a1 += xs * g0[1]; a2 += xs * g0[2]; a3 += xs * g0[3];
      a4 += xs * g1[0]; a5 += xs * g1[1]; a6 += xs * g1[2]; a7 += xs * g1[3];
    }
  }
#pragma unroll
  for (int s = 32; s > 0; s >>= 1) {
    a0 += __shfl_xor(a0, s, 64); a1 += __shfl_xor(a1, s, 64);
    a2 += __shfl_xor(a2, s, 64); a3 += __shfl_xor(a3, s, 64);
    a4 += __shfl_xor(a4, s, 64); a5 += __shfl_xor(a5, s, 64);
    a6 += __shfl_xor(a6, s, 64); a7 += __shfl_xor(a7, s, 64);
  }
  if (lane == 0) {
    float p_[NE] = {a0, a1, a2, a3, a4, a5, a6, a7};
    float m = p_[0];
#pragma unroll
    for (int e = 1; e < NE; ++e) m = fmaxf(m, p_[e]);
    float ssum = 0.f;
#pragma unroll
    for (int e = 0; e < NE; ++e) { p_[e] = __expf(p_[e] - m); ssum += p_[e]; }
    float inv = 1.f / ssum;
    int i1 = 0; float b1 = p_[0];
#pragma unroll
    for (int e = 1; e < NE; ++e) if (p_[e] > b1) { b1 = p_[e]; i1 = e; }
    int i2 = -1; float b2 = -1.f;
#pragma unroll
    for (int e = 0; e < NE; ++e) if (e != i1 && p_[e] > b2) { b2 = p_[e]; i2 = e; }
    int s1 = atomicAdd(&cnt[i1], 1);
    ltok[i1 * TK + s1] = tok; lw[i1 * TK + s1] = b1 * inv;
    int s2 = atomicAdd(&cnt[i2], 1);
    ltok[i2 * TK + s2] = tok; lw[i2 * TK + s2] = b2 * inv;
  }
}

__global__ void k_prefix(const int* __restrict__ cnt, int* __restrict__ off) {
  if (threadIdx.x == 0) {
    int a = 0;
#pragma unroll
    for (int e = 0; e < NE; ++e) { off[e] = a; a += cnt[e]; }
    off[NE] = a;
  }
}

// ---------------- GEMM1: H = silu(X W1) * (X W3) * w  (bf16 out) ----------------
__global__ __launch_bounds__(256, 2)
void k_gemm1(const float* __restrict__ x, const float* __restrict__ w1g,
             const float* __restrict__ w3g, const int* __restrict__ cnt,
             const int* __restrict__ off, const int* __restrict__ ltok,
             const float* __restrict__ lw, unsigned short* __restrict__ H) {
  const int e = blockIdx.z;
  const int ce = cnt[e];
  const int m0 = blockIdx.y * BM;
  if (m0 >= ce) return;
  const int n0 = blockIdx.x * BN;
  const int tid = threadIdx.x;
  const int lane = tid & 63;
  const int wv = tid >> 6;
  const int wr = wv >> 1, wc = wv & 1;
  const float* W1 = w1g + (size_t)e * DD * FF;
  const float* W3 = w3g + (size_t)e * DD * FF;
  const int base = off[e];

  __shared__ unsigned short As[BM * BK];
  __shared__ unsigned short B1s[BN * BK];
  __shared__ unsigned short B3s[BN * BK];

  const int arow = tid >> 1;
  const int ahalf = tid & 1;
  const int gmrow = m0 + arow;
  const float* xrow = (gmrow < ce) ? (x + (size_t)ltok[e * TK + gmrow] * DD) : nullptr;

  f32x4 acc1[4][4], acc3[4][4];
#pragma unroll
  for (int m = 0; m < 4; ++m)
#pragma unroll
    for (int n = 0; n < 4; ++n)
#pragma unroll
      for (int j = 0; j < 4; ++j) { acc1[m][n][j] = 0.f; acc3[m][n][j] = 0.f; }

  for (int kt = 0; kt < DD / BK; ++kt) {
    const int k0 = kt * BK;
    // global loads: A rows + W1 (4x4 transpose blocks)
    f32x4 av[8];
#pragma unroll
    for (int j = 0; j < 8; ++j) {
      if (xrow) av[j] = *(const f32x4*)(xrow + k0 + ahalf * 32 + j * 4);
      else { av[j][0] = 0.f; av[j][1] = 0.f; av[j][2] = 0.f; av[j][3] = 0.f; }
    }
    f32x4 w1v[2][4];
#pragma unroll
    for (int b = 0; b < 2; ++b) {
      const int bi = tid + (b << 8);
      const int dblk = bi >> 5, fblk = bi & 31;
      const float* p = W1 + (size_t)(k0 + dblk * 4) * FF + (n0 + fblk * 4);
#pragma unroll
      for (int r = 0; r < 4; ++r) w1v[b][r] = *(const f32x4*)(p + (size_t)r * FF);
    }
    __syncthreads();
#pragma unroll
    for (int j = 0; j < 8; ++j) {
      int boff = (arow * 128 + ahalf * 64 + j * 8) ^ SWZ(arow);
      *(bf16x4*)((char*)As + boff) = pack4(av[j][0], av[j][1], av[j][2], av[j][3]);
    }
#pragma unroll
    for (int b = 0; b < 2; ++b) {
      const int bi = tid + (b << 8);
      const int dblk = bi >> 5, fblk = bi & 31;
#pragma unroll
      for (int j = 0; j < 4; ++j) {
        int f = fblk * 4 + j;
        int boff = (f * 128 + dblk * 8) ^ SWZ(f);
        *(bf16x4*)((char*)B1s + boff) =
            pack4(w1v[0 + 0][0][j], w1v[b][1][j], w1v[b][2][j], w1v[b][3][j]);
        // NOTE: first arg must be w1v[b][0][j]; fixed below by recompute
        *(bf16x4*)((char*)B1s + boff) =
            pack4(w1v[b][0][j], w1v[b][1][j], w1v[b][2][j], w1v[b][3][j]);
      }
    }
    // W3: load after A/W1 writes to cap live registers
    f32x4 w3v[2][4];
#pragma unroll
    for (int b = 0; b < 2; ++b) {
      const int bi = tid + (b << 8);
      const int dblk = bi >> 5, fblk = bi & 31;
      const float* p = W3 + (size_t)(k0 + dblk * 4) * FF + (n0 + fblk * 4);
#pragma unroll
      for (int r = 0; r < 4; ++r) w3v[b][r] = *(const f32x4*)(p + (size_t)r * FF);
    }
#pragma unroll
    for (int b = 0; b < 2; ++b) {
      const int bi = tid + (b << 8);
      const int dblk = bi >> 5, fblk = bi & 31;
#pragma unroll
      for (int j = 0; j < 4; ++j) {
        int f = fblk * 4 + j;
        int boff = (f * 128 + dblk * 8) ^ SWZ(f);
        *(bf16x4*)((char*)B3s + boff) =
            pack4(w3v[b][0][j], w3v[b][1][j], w3v[b][2][j], w3v[b][3][j]);
      }
    }
    __syncthreads();
#pragma unroll
    for (int kk = 0; kk < 2; ++kk) {
      const int kbyte = kk * 64 + (lane >> 4) * 16;
      bf16x8 af[4], b1f[4], b3f[4];
#pragma unroll
      for (int m = 0; m < 4; ++m) af[m] = lds_frag(As, wr * 64 + m * 16 + (lane & 15), kbyte);
#pragma unroll
      for (int n = 0; n < 4; ++n) {
        int row = wc * 64 + n * 16 + (lane & 15);
        b1f[n] = lds_frag(B1s, row, kbyte);
        b3f[n] = lds_frag(B3s, row, kbyte);
      }
#pragma unroll
      for (int m = 0; m < 4; ++m)
#pragma unroll
        for (int n = 0; n < 4; ++n) {
          acc1[m][n] = __builtin_amdgcn_mfma_f32_16x16x32_bf16(af[m], b1f[n], acc1[m][n], 0, 0, 0);
          acc3[m][n] = __builtin_amdgcn_mfma_f32_16x16x32_bf16(af[m], b3f[n], acc3[m][n], 0, 0, 0);
        }
    }
  }
  // epilogue: silu(acc1)*acc3*combine_weight -> H (bf16)
#pragma unroll
  for (int m = 0; m < 4; ++m) {
    const int rbase = wr * 64 + m * 16 + ((lane >> 4) << 2);
    float wts[4]; bool val[4];
#pragma unroll
    for (int j = 0; j < 4; ++j) {
      int r = m0 + rbase + j;
      val[j] = r < ce;
      wts[j] = val[j] ? lw[e * TK + r] : 0.f;
    }
#pragma unroll
    for (int n = 0; n < 4; ++n) {
      const int col = n0 + wc * 64 + n * 16 + (lane & 15);
#pragma unroll
      for (int j = 0; j < 4; ++j) {
        if (!val[j]) continue;
        float s1 = acc1[m][n][j], s3 = acc3[m][n][j];
        float h = s1 / (1.f + __expf(-s1)) * s3 * wts[j];
        H[(size_t)(base + m0 + rbase + j) * FF + col] = f2bf(h);
      }
    }
  }
}

// ---------------- GEMM2: out += H W2 (scatter by token, fp32 atomics) ----------------
__global__ __launch_bounds__(256, 2)
void k_gemm2(const unsigned short* __restrict__ H, const float* __restrict__ w2g,
             const int* __restrict__ cnt, const int* __restrict__ off,
             const int* __restrict__ ltok, float* __restrict__ out) {
  const int e = blockIdx.z;
  const int ce = cnt[e];
  const int m0 = blockIdx.y * BM;
  if (m0 >= ce) return;
  const int n0 = blockIdx.x * BN;
  const int tid = threadIdx.x;
  const int lane = tid & 63;
  const int wv = tid >> 6;
  const int wr = wv >> 1, wc = wv & 1;
  const float* W2 = w2g + (size_t)e * FF * DD;
  const int base = off[e];

  __shared__ unsigned short As[BM * BK];
  __shared__ unsigned short Bs[BN * BK];

  const int arow = tid >> 1;
  const int ahalf = tid & 1;
  const bool aval = (m0 + arow) < ce;
  const unsigned short* hrow = H + (size_t)(base + m0 + arow) * FF;

  f32x4 acc[4][4];
#pragma unroll
  for (int m = 0; m < 4; ++m)
#pragma unroll
    for (int n = 0; n < 4; ++n)
#pragma unroll
      for (int j = 0; j < 4; ++j) acc[m][n][j] = 0.f;

  for (int kt = 0; kt < FF / BK; ++kt) {
    const int k0 = kt * BK;
    bf16x8 av[4];
#pragma unroll
    for (int j = 0; j < 4; ++j) {
      if (aval) av[j] = *(const bf16x8*)(hrow + k0 + ahalf * 32 + j * 8);
      else {
#pragma unroll
        for (int q = 0; q < 8; ++q) av[j][q] = 0;
      }
    }
    f32x4 wvv[2][4];
#pragma unroll
    for (int b = 0; b < 2; ++b) {
      const int bi = tid + (b << 8);
      const int kblk = bi >> 5, nblk = bi & 31;
      const float* p = W2 + (size_t)(k0 + kblk * 4) * DD + (n0 + nblk * 4);
#pragma unroll
      for (int r = 0; r < 4; ++r) wvv[b][r] = *(const f32x4*)(p + (size_t)r * DD);
    }
    __syncthreads();
#pragma unroll
    for (int j = 0; j < 4; ++j) {
      int boff = (arow * 128 + ahalf * 64 + j * 16) ^ SWZ(arow);
      *(bf16x8*)((char*)As + boff) = av[j];
    }
#pragma unroll
    for (int b = 0; b < 2; ++b) {
      const int bi = tid + (b << 8);
      const int kblk = bi >> 5, nblk = bi & 31;
#pragma unroll
      for (int j = 0; j < 4; ++j) {
        int f = nblk * 4 + j;
        int boff = (f * 128 + kblk * 8) ^ SWZ(f);
        *(bf16x4*)((char*)Bs + boff) =
            pack4(wvv[b][0][j], wvv[b][1][j], wvv[b][2][j], wvv[b][3][j]);
      }
    }
    __syncthreads();
#pragma unroll
    for (int kk = 0; kk < 2; ++kk) {
      const int kbyte = kk * 64 + (lane >> 4) * 16;
      bf16x8 af[4], bf[4];
#pragma unroll
      for (int m = 0; m < 4; ++m) af[m] = lds_frag(As, wr * 64 + m * 16 + (lane & 15), kbyte);
#pragma unroll
      for (int n = 0; n < 4; ++n) bf[n] = lds_frag(Bs, wc * 64 + n * 16 + (lane & 15), kbyte);
#pragma unroll
      for (int m = 0; m < 4; ++m)
#pragma unroll
        for (int n = 0; n < 4; ++n)
          acc[m][n] = __builtin_amdgcn_mfma_f32_16x16x32_bf16(af[m], bf[n], acc[m][n], 0, 0, 0);
    }
  }
#pragma unroll
  for (int m = 0; m < 4; ++m) {
    const int rbase = wr * 64 + m * 16 + ((lane >> 4) << 2);
    int toks[4]; bool val[4];
#pragma unroll
    for (int j = 0; j < 4; ++j) {
      int r = m0 + rbase + j;
      val[j] = r < ce;
      toks[j] = val[j] ? ltok[e * TK + r] : 0;
    }
#pragma unroll
    for (int n = 0; n < 4; ++n) {
      const int col = n0 + wc * 64 + n * 16 + (lane & 15);
#pragma unroll
      for (int j = 0; j < 4; ++j)
        if (val[j]) atomicAdd(out + (size_t)toks[j] * DD + col, acc[m][n][j]);
    }
  }
}

extern "C" void kernel_launch(void* const* d_in, const int* in_sizes, int n_in,
                              void* d_out, int out_size, void* d_ws, size_t ws_size,
                              hipStream_t stream) {
  const float* x  = (const float*)d_in[0];
  const float* gw = (const float*)d_in[1];
  const float* w1 = (const float*)d_in[2];
  const float* w3 = (const float*)d_in[3];
  const float* w2 = (const float*)d_in[4];
  float* out = (float*)d_out;

  char* ws = (char*)d_ws;
  int*   cnt  = (int*)(ws);
  int*   off  = (int*)(ws + 64);
  int*   ltok = (int*)(ws + 256);
  float* lw   = (float*)(ws + 256 + (size_t)NE * TK * 4);
  unsigned short* H = (unsigned short*)(ws + (1 << 20));
  const size_t need = (1u << 20) + (size_t)2 * TK * FF * 2;  // ~68 MB
  if (ws_size < need) return;  // workspace too small — will fail loudly

  hipMemsetAsync(cnt, 0, 64, stream);
  hipMemsetAsync(d_out, 0, (size_t)out_size * 4, stream);
  k_router<<<dim3(TK / 4), 256, 0, stream>>>(x, gw, cnt, ltok, lw);
  k_prefix<<<dim3(1), 64, 0, stream>>>(cnt, off);
  k_gemm1<<<dim3(FF / BN, TK / BM, NE), 256, 0, stream>>>(x, w1, w3, cnt, off, ltok, lw, H);
  k_gemm2<<<dim3(DD / BN, TK / BM, NE), 256, 0, stream>>>(H, w2, cnt, off, ltok, out);
}

// Round 2
// 979.110 us; speedup vs baseline: 1.1425x; 1.1425x over previous
//
#include <hip/hip_runtime.h>
#include <hip/hip_bf16.h>

#define TK 4096   // tokens
#define DD 2048   // hidden
#define FF 4096   // intermediate
#define NE 8      // experts
#define BM 128
#define BN 128
#define BK 32

typedef __attribute__((ext_vector_type(8))) short bf16x8;
typedef __attribute__((ext_vector_type(4))) short bf16x4;
typedef __attribute__((ext_vector_type(4))) float f32x4;

__device__ __forceinline__ unsigned short f2bf(float f) {
  // compiler emits v_cvt_pk_bf16_f32 for pairs (RNE) — do NOT hand-roll
  return __builtin_bit_cast(unsigned short, __float2bfloat16(f));
}

// LDS tiles are [row][32 bf16] = 64B rows. Swizzle the 16B slot index by
// (row&3)^((row>>2)&3): b128 frag reads land <=2-way (free), 8B writes stay
// within one slot.
__device__ __forceinline__ int swzoff(int row, int bir) {
  int slot = (bir >> 4) ^ ((row & 3) ^ ((row >> 2) & 3));
  return row * 64 + (slot << 4) + (bir & 15);
}
__device__ __forceinline__ bf16x8 frag(const unsigned short* base, int row, int kbyte) {
  return *(const bf16x8*)((const char*)base + swzoff(row, kbyte));
}
__device__ __forceinline__ void put8(unsigned short* b, int row, int bir, bf16x4 v) {
  *(bf16x4*)((char*)b + swzoff(row, bir)) = v;
}
__device__ __forceinline__ void put16(unsigned short* b, int row, int bir, bf16x8 v) {
  *(bf16x8*)((char*)b + swzoff(row, bir)) = v;
}

// ---------------- router: 1 wave per token ----------------
__global__ void k_router(const float* __restrict__ x, const float* __restrict__ gw,
                         int* __restrict__ cnt, int* __restrict__ ltok,
                         float* __restrict__ lw) {
  int tok = (blockIdx.x * blockDim.x + threadIdx.x) >> 6;
  int lane = threadIdx.x & 63;
  if (tok >= TK) return;
  const float* xr = x + (size_t)tok * DD;
  float a0=0,a1=0,a2=0,a3=0,a4=0,a5=0,a6=0,a7=0;
  for (int p = 0; p < DD / 256; ++p) {
    int d0 = p * 256 + lane * 4;
    f32x4 xv = *(const f32x4*)(xr + d0);
#pragma unroll
    for (int j = 0; j < 4; ++j) {
      float xs = xv[j];
      const f32x4* g = (const f32x4*)(gw + (size_t)(d0 + j) * NE);
      f32x4 g0 = g[0], g1 = g[1];
      a0 += xs * g0[0]; a1 += xs * g0[1]; a2 += xs * g0[2]; a3 += xs * g0[3];
      a4 += xs * g1[0]; a5 += xs * g1[1]; a6 += xs * g1[2]; a7 += xs * g1[3];
    }
  }
#pragma unroll
  for (int s = 32; s > 0; s >>= 1) {
    a0 += __shfl_xor(a0, s, 64); a1 += __shfl_xor(a1, s, 64);
    a2 += __shfl_xor(a2, s, 64); a3 += __shfl_xor(a3, s, 64);
    a4 += __shfl_xor(a4, s, 64); a5 += __shfl_xor(a5, s, 64);
    a6 += __shfl_xor(a6, s, 64); a7 += __shfl_xor(a7, s, 64);
  }
  if (lane == 0) {
    float p_[NE] = {a0, a1, a2, a3, a4, a5, a6, a7};
    float m = p_[0];
#pragma unroll
    for (int e = 1; e < NE; ++e) m = fmaxf(m, p_[e]);
    float ssum = 0.f;
#pragma unroll
    for (int e = 0; e < NE; ++e) { p_[e] = __expf(p_[e] - m); ssum += p_[e]; }
    float inv = 1.f / ssum;
    int i1 = 0; float b1 = p_[0];
#pragma unroll
    for (int e = 1; e < NE; ++e) if (p_[e] > b1) { b1 = p_[e]; i1 = e; }
    int i2 = -1; float b2 = -1.f;
#pragma unroll
    for (int e = 0; e < NE; ++e) if (e != i1 && p_[e] > b2) { b2 = p_[e]; i2 = e; }
    int s1 = atomicAdd(&cnt[i1], 1);
    ltok[i1 * TK + s1] = tok; lw[i1 * TK + s1] = b1 * inv;
    int s2 = atomicAdd(&cnt[i2], 1);
    ltok[i2 * TK + s2] = tok; lw[i2 * TK + s2] = b2 * inv;
  }
}

__global__ void k_prefix(const int* __restrict__ cnt, int* __restrict__ off) {
  if (threadIdx.x == 0) {
    int a = 0;
#pragma unroll
    for (int e = 0; e < NE; ++e) { off[e] = a; a += cnt[e]; }
    off[NE] = a;
  }
}

// ---------------- GEMM1: H = silu(X W1) * (X W3) * w  (bf16 out) ----------------
// 2-phase pipeline: issue loads(t+1) -> barrier -> ds_read+MFMA(t) -> cvt+ds_write(t+1)
__global__ __launch_bounds__(256, 2)
void k_gemm1(const float* __restrict__ x, const float* __restrict__ w1g,
             const float* __restrict__ w3g, const int* __restrict__ cnt,
             const int* __restrict__ off, const int* __restrict__ ltok,
             const float* __restrict__ lw, unsigned short* __restrict__ H) {
  const int e = blockIdx.z;
  const int ce = cnt[e];
  const int m0 = blockIdx.y * BM;
  if (m0 >= ce) return;
  const int n0 = blockIdx.x * BN;
  const int tid = threadIdx.x, lane = tid & 63, wv = tid >> 6;
  const int wr = wv >> 1, wc = wv & 1;
  const float* W1 = w1g + (size_t)e * DD * FF;
  const float* W3 = w3g + (size_t)e * DD * FF;
  const int base = off[e];

  __shared__ unsigned short As[2][BM * BK];
  __shared__ unsigned short B1s[2][BN * BK];
  __shared__ unsigned short B3s[2][BN * BK];

  const int arow = tid >> 1, ah = tid & 1;
  const float* xrow = (m0 + arow < ce) ? (x + (size_t)ltok[e * TK + (m0 + arow)] * DD) : nullptr;
  const int dblk = tid >> 5, fblk = tid & 31;  // 8 x 32 4x4-blocks of B

  f32x4 acc1[4][4], acc3[4][4];
#pragma unroll
  for (int m = 0; m < 4; ++m)
#pragma unroll
    for (int n = 0; n < 4; ++n)
#pragma unroll
      for (int j = 0; j < 4; ++j) { acc1[m][n][j] = 0.f; acc3[m][n][j] = 0.f; }

  f32x4 av[4], v1[4], v3[4];

  auto LOAD = [&](int kt) {
    const int k0 = kt * BK;
#pragma unroll
    for (int j = 0; j < 4; ++j) {
      if (xrow) av[j] = *(const f32x4*)(xrow + k0 + ah * 16 + j * 4);
      else { av[j][0] = 0.f; av[j][1] = 0.f; av[j][2] = 0.f; av[j][3] = 0.f; }
    }
    const float* p1 = W1 + (size_t)(k0 + dblk * 4) * FF + (n0 + fblk * 4);
    const float* p3 = W3 + (size_t)(k0 + dblk * 4) * FF + (n0 + fblk * 4);
#pragma unroll
    for (int r = 0; r < 4; ++r) {
      v1[r] = *(const f32x4*)(p1 + (size_t)r * FF);
      v3[r] = *(const f32x4*)(p3 + (size_t)r * FF);
    }
  };
  auto STORE = [&](int buf) {
#pragma unroll
    for (int j = 0; j < 4; ++j) {
      bf16x4 t;
      t[0] = (short)f2bf(av[j][0]); t[1] = (short)f2bf(av[j][1]);
      t[2] = (short)f2bf(av[j][2]); t[3] = (short)f2bf(av[j][3]);
      put8(As[buf], arow, ah * 32 + j * 8, t);
    }
#pragma unroll
    for (int j = 0; j < 4; ++j) {   // transpose 4x4: col j of the block
      bf16x4 t1, t3;
      t1[0] = (short)f2bf(v1[0][j]); t1[1] = (short)f2bf(v1[1][j]);
      t1[2] = (short)f2bf(v1[2][j]); t1[3] = (short)f2bf(v1[3][j]);
      t3[0] = (short)f2bf(v3[0][j]); t3[1] = (short)f2bf(v3[1][j]);
      t3[2] = (short)f2bf(v3[2][j]); t3[3] = (short)f2bf(v3[3][j]);
      put8(B1s[buf], fblk * 4 + j, dblk * 8, t1);
      put8(B3s[buf], fblk * 4 + j, dblk * 8, t3);
    }
  };

  LOAD(0);
  STORE(0);
  int cur = 0;
  const int NT = DD / BK;
  for (int kt = 0; kt < NT; ++kt) {
    if (kt + 1 < NT) LOAD(kt + 1);
    __syncthreads();
    const int kb = (lane >> 4) * 16;
    bf16x8 af[4];
#pragma unroll
    for (int m = 0; m < 4; ++m) af[m] = frag(As[cur], wr * 64 + m * 16 + (lane & 15), kb);
#pragma unroll
    for (int n = 0; n < 4; ++n) {
      const int brow = wc * 64 + n * 16 + (lane & 15);
      bf16x8 b1 = frag(B1s[cur], brow, kb);
      bf16x8 b3 = frag(B3s[cur], brow, kb);
#pragma unroll
      for (int m = 0; m < 4; ++m) {
        acc1[m][n] = __builtin_amdgcn_mfma_f32_16x16x32_bf16(af[m], b1, acc1[m][n], 0, 0, 0);
        acc3[m][n] = __builtin_amdgcn_mfma_f32_16x16x32_bf16(af[m], b3, acc3[m][n], 0, 0, 0);
      }
    }
    if (kt + 1 < NT) STORE(cur ^ 1);
    cur ^= 1;
  }

  // epilogue: silu(acc1)*acc3*combine_weight -> H (bf16)
#pragma unroll
  for (int m = 0; m < 4; ++m) {
    const int rbase = wr * 64 + m * 16 + ((lane >> 4) << 2);
    float wts[4]; bool val[4];
#pragma unroll
    for (int j = 0; j < 4; ++j) {
      int r = m0 + rbase + j;
      val[j] = r < ce;
      wts[j] = val[j] ? lw[e * TK + r] : 0.f;
    }
#pragma unroll
    for (int n = 0; n < 4; ++n) {
      const int col = n0 + wc * 64 + n * 16 + (lane & 15);
#pragma unroll
      for (int j = 0; j < 4; ++j) {
        if (!val[j]) continue;
        float s1 = acc1[m][n][j], s3 = acc3[m][n][j];
        float h = s1 / (1.f + __expf(-s1)) * s3 * wts[j];
        H[(size_t)(base + m0 + rbase + j) * FF + col] = f2bf(h);
      }
    }
  }
}

// ---------------- GEMM2: out += H W2 (scatter by token, fp32 atomics) ----------------
__global__ __launch_bounds__(256, 2)
void k_gemm2(const unsigned short* __restrict__ H, const float* __restrict__ w2g,
             const int* __restrict__ cnt, const int* __restrict__ off,
             const int* __restrict__ ltok, float* __restrict__ out) {
  const int e = blockIdx.z;
  const int ce = cnt[e];
  const int m0 = blockIdx.y * BM;
  if (m0 >= ce) return;
  const int n0 = blockIdx.x * BN;
  const int tid = threadIdx.x, lane = tid & 63, wv = tid >> 6;
  const int wr = wv >> 1, wc = wv & 1;
  const float* W2 = w2g + (size_t)e * FF * DD;
  const int base = off[e];

  __shared__ unsigned short As[2][BM * BK];
  __shared__ unsigned short Bs[2][BN * BK];

  const int arow = tid >> 1, ah = tid & 1;
  const bool aval = (m0 + arow) < ce;
  const unsigned short* hrow = H + (size_t)(base + m0 + arow) * FF;
  const int kblk = tid >> 5, nblk = tid & 31;

  f32x4 acc[4][4];
#pragma unroll
  for (int m = 0; m < 4; ++m)
#pragma unroll
    for (int n = 0; n < 4; ++n)
#pragma unroll
      for (int j = 0; j < 4; ++j) acc[m][n][j] = 0.f;

  bf16x8 av2[2];
  f32x4 wv2[4];

  auto LOAD = [&](int kt) {
    const int k0 = kt * BK;
#pragma unroll
    for (int j = 0; j < 2; ++j) {
      if (aval) av2[j] = *(const bf16x8*)(hrow + k0 + ah * 16 + j * 8);
      else {
#pragma unroll
        for (int q = 0; q < 8; ++q) av2[j][q] = 0;
      }
    }
    const float* p = W2 + (size_t)(k0 + kblk * 4) * DD + (n0 + nblk * 4);
#pragma unroll
    for (int r = 0; r < 4; ++r) wv2[r] = *(const f32x4*)(p + (size_t)r * DD);
  };
  auto STORE = [&](int buf) {
#pragma unroll
    for (int j = 0; j < 2; ++j) put16(As[buf], arow, ah * 32 + j * 16, av2[j]);
#pragma unroll
    for (int j = 0; j < 4; ++j) {
      bf16x4 t;
      t[0] = (short)f2bf(wv2[0][j]); t[1] = (short)f2bf(wv2[1][j]);
      t[2] = (short)f2bf(wv2[2][j]); t[3] = (short)f2bf(wv2[3][j]);
      put8(Bs[buf], nblk * 4 + j, kblk * 8, t);
    }
  };

  LOAD(0);
  STORE(0);
  int cur = 0;
  const int NT = FF / BK;
  for (int kt = 0; kt < NT; ++kt) {
    if (kt + 1 < NT) LOAD(kt + 1);
    __syncthreads();
    const int kb = (lane >> 4) * 16;
    bf16x8 af[4];
#pragma unroll
    for (int m = 0; m < 4; ++m) af[m] = frag(As[cur], wr * 64 + m * 16 + (lane & 15), kb);
#pragma unroll
    for (int n = 0; n < 4; ++n) {
      bf16x8 bf = frag(Bs[cur], wc * 64 + n * 16 + (lane & 15), kb);
#pragma unroll
      for (int m = 0; m < 4; ++m)
        acc[m][n] = __builtin_amdgcn_mfma_f32_16x16x32_bf16(af[m], bf, acc[m][n], 0, 0, 0);
    }
    if (kt + 1 < NT) STORE(cur ^ 1);
    cur ^= 1;
  }

#pragma unroll
  for (int m = 0; m < 4; ++m) {
    const int rbase = wr * 64 + m * 16 + ((lane >> 4) << 2);
    int toks[4]; bool val[4];
#pragma unroll
    for (int j = 0; j < 4; ++j) {
      int r = m0 + rbase + j;
      val[j] = r < ce;
      toks[j] = val[j] ? ltok[e * TK + r] : 0;
    }
#pragma unroll
    for (int n = 0; n < 4; ++n) {
      const int col = n0 + wc * 64 + n * 16 + (lane & 15);
#pragma unroll
      for (int j = 0; j < 4; ++j)
        if (val[j]) atomicAdd(out + (size_t)toks[j] * DD + col, acc[m][n][j]);
    }
  }
}

extern "C" void kernel_launch(void* const* d_in, const int* in_sizes, int n_in,
                              void* d_out, int out_size, void* d_ws, size_t ws_size,
                              hipStream_t stream) {
  const float* x  = (const float*)d_in[0];
  const float* gw = (const float*)d_in[1];
  const float* w1 = (const float*)d_in[2];
  const float* w3 = (const float*)d_in[3];
  const float* w2 = (const float*)d_in[4];
  float* out = (float*)d_out;

  char* ws = (char*)d_ws;
  int*   cnt  = (int*)(ws);
  int*   off  = (int*)(ws + 64);
  int*   ltok = (int*)(ws + 256);
  float* lw   = (float*)(ws + 256 + (size_t)NE * TK * 4);
  unsigned short* H = (unsigned short*)(ws + (1 << 20));
  const size_t need = (1u << 20) + (size_t)2 * TK * FF * 2;  // ~68 MB
  if (ws_size < need) return;

  hipMemsetAsync(cnt, 0, 64, stream);
  hipMemsetAsync(d_out, 0, (size_t)out_size * 4, stream);
  k_router<<<dim3(TK / 4), 256, 0, stream>>>(x, gw, cnt, ltok, lw);
  k_prefix<<<dim3(1), 64, 0, stream>>>(cnt, off);
  k_gemm1<<<dim3(FF / BN, TK / BM, NE), 256, 0, stream>>>(x, w1, w3, cnt, off, ltok, lw, H);
  k_gemm2<<<dim3(DD / BN, TK / BM, NE), 256, 0, stream>>>(H, w2, cnt, off, ltok, out);
}